// Round 1
// baseline (20941.502 us; speedup 1.0000x reference)
//
#include <hip/hip_runtime.h>
#include <hip/hip_bf16.h>

#define B_ 64
#define T_ 512
#define D_ 256
#define H_ 1024

typedef __attribute__((ext_vector_type(8))) short short8;
typedef __attribute__((ext_vector_type(4))) float floatx4;

__device__ __forceinline__ unsigned short f2bf(float f){
  unsigned u = __builtin_bit_cast(unsigned, f);
  u = (u + 0x7fffu + ((u >> 16) & 1u)) >> 16;
  return (unsigned short)u;
}

__device__ __forceinline__ short8 pack8(floatx4 a, floatx4 b){
  short8 r;
  r[0]=(short)f2bf(a[0]); r[1]=(short)f2bf(a[1]); r[2]=(short)f2bf(a[2]); r[3]=(short)f2bf(a[3]);
  r[4]=(short)f2bf(b[0]); r[5]=(short)f2bf(b[1]); r[6]=(short)f2bf(b[2]); r[7]=(short)f2bf(b[3]);
  return r;
}

__device__ __forceinline__ float sigm(float v){ return 1.f/(1.f+__expf(-v)); }
__device__ __forceinline__ float tanh_f(float v){ return 1.f - 2.f/(1.f+__expf(2.f*v)); }

// LAYER 0: K = 256 (x) + 1024 (h0) = 1280.  LAYER 1: K = 1024 (h0) + 1024 (h1) = 2048.
template<int LAYER>
__device__ __forceinline__ void run_lstm(
    const float* __restrict__ x,
    const float* __restrict__ Wi, const float* __restrict__ Wh,
    const float* __restrict__ bi, const float* __restrict__ bh,
    unsigned* cnt, unsigned* epoch,
    unsigned short* h0r, unsigned short* h1r, float* h1f,
    int jbase, float* partial /*[4][64][33]*/, float* c_st /*[64*8]*/, float* biasv /*[32]*/)
{
  constexpr int KTOT = LAYER ? 2048 : 1280;
  constexpr int KW   = KTOT / 4;     // per-wave K slice
  constexpr int NK   = KW / 32;      // k-steps of 32 per wave (16 or 10)
  constexpr int KI   = LAYER ? 1024 : 256;  // boundary Wi-part / Wh-part

  const int tid  = threadIdx.x;
  const int wave = tid >> 6;
  const int lane = tid & 63;
  const int bid  = blockIdx.x;
  const int n15  = lane & 15;
  const int kq   = (lane >> 4) * 8;

  // ---- one-time: load this block's weight fragments into registers (bf16)
  short8 bfr[2][NK];
  #pragma unroll
  for (int nt = 0; nt < 2; nt++){
    int n = nt*16 + n15;
    int q = n >> 3, jj = n & 7;
    int row = q*H_ + jbase + jj;
    #pragma unroll
    for (int ks = 0; ks < NK; ks++){
      int k = wave*KW + ks*32 + kq;
      const float* s = (k < KI) ? (Wi + (size_t)row*KI + k)
                                : (Wh + (size_t)row*H_ + (k - KI));
      floatx4 f0 = *(const floatx4*)s;
      floatx4 f1 = *(const floatx4*)(s + 4);
      bfr[nt][ks] = pack8(f0, f1);
    }
  }
  if (tid < 32){
    int n = tid, q = n >> 3, jj = n & 7, col = q*H_ + jbase + jj;
    biasv[n] = bi[col] + bh[col];
  }
  for (int i = tid; i < 512; i += 256) c_st[i] = 0.f;
  __syncthreads();

  // ---- sequential loop: 513 iterations, layer1 lags layer0 by one step
  for (int it = 0; it <= T_; ++it){
    const bool active = LAYER ? (it >= 1) : (it < T_);
    const int t = LAYER ? it - 1 : it;   // timestep this block computes

    if (active){
      floatx4 acc[4][2];
      #pragma unroll
      for (int mt = 0; mt < 4; mt++)
        #pragma unroll
        for (int nt = 0; nt < 2; nt++)
          acc[mt][nt] = (floatx4)0.f;

      // layer0 reads h0[t-1] (slot (t+1)&1); layer1 reads h0[t] (slot t&1), h1[t-1] (slot (t+1)&1)
      const unsigned short* srcA_h0 = h0r + (size_t)(LAYER ? (t & 1) : ((t + 1) & 1)) * 65536;
      const unsigned short* srcA_h1 = h1r + (size_t)((t + 1) & 1) * 65536;

      #pragma unroll
      for (int ks = 0; ks < NK; ks++){
        const int kb = wave*KW + ks*32;
        const int kk = kb + kq;
        short8 afr[4];
        if constexpr (LAYER == 0){
          if (kb < 256){
            #pragma unroll
            for (int mt = 0; mt < 4; mt++){
              int b = mt*16 + n15;
              const float* xs = x + ((size_t)(b*T_ + t))*D_ + kk;
              floatx4 f0 = *(const floatx4*)xs;
              floatx4 f1 = *(const floatx4*)(xs + 4);
              afr[mt] = pack8(f0, f1);
            }
          } else {
            const unsigned short* base = srcA_h0 + (kk - 256);
            #pragma unroll
            for (int mt = 0; mt < 4; mt++){
              int b = mt*16 + n15;
              afr[mt] = *(const short8*)(base + (size_t)b*H_);
            }
          }
        } else {
          const unsigned short* base = (kb < 1024) ? (srcA_h0 + kk) : (srcA_h1 + (kk - 1024));
          #pragma unroll
          for (int mt = 0; mt < 4; mt++){
            int b = mt*16 + n15;
            afr[mt] = *(const short8*)(base + (size_t)b*H_);
          }
        }
        #pragma unroll
        for (int mt = 0; mt < 4; mt++)
          #pragma unroll
          for (int nt = 0; nt < 2; nt++)
            acc[mt][nt] = __builtin_amdgcn_mfma_f32_16x16x32_bf16(afr[mt], bfr[nt][ks], acc[mt][nt], 0, 0, 0);
      }

      // spill per-wave partials to LDS (C layout: col = lane&15, row = (lane>>4)*4 + r)
      #pragma unroll
      for (int mt = 0; mt < 4; mt++)
        #pragma unroll
        for (int nt = 0; nt < 2; nt++)
          #pragma unroll
          for (int r = 0; r < 4; r++){
            int b = mt*16 + (lane >> 4)*4 + r;
            int n = nt*16 + n15;
            partial[((size_t)wave*64 + b)*33 + n] = acc[mt][nt][r];
          }
    }
    __syncthreads();

    if (active){
      unsigned short* dst = (LAYER ? h1r : h0r) + (size_t)(t & 1) * 65536;
      for (int p = tid; p < 512; p += 256){
        int b = p >> 3, jj = p & 7;
        float g[4];
        #pragma unroll
        for (int q = 0; q < 4; q++){
          int n = q*8 + jj;
          g[q] = partial[(0*64 + b)*33 + n] + partial[(1*64 + b)*33 + n]
               + partial[(2*64 + b)*33 + n] + partial[(3*64 + b)*33 + n] + biasv[n];
        }
        float co = c_st[p];
        float si = sigm(g[0]);
        float sf = sigm(g[1]);
        float tg = tanh_f(g[2]);
        float so = sigm(g[3]);
        float cn = sf*co + si*tg;
        float hn = so*tanh_f(cn);
        c_st[p] = cn;
        dst[(size_t)b*H_ + jbase + jj] = f2bf(hn);
        if (LAYER) h1f[(size_t)b*H_ + jbase + jj] = hn;
      }
    }

    // ---- device-wide step barrier (two-level: 8 counters -> epoch)
    __threadfence();       // vmcnt drain + L2 writeback (agent scope)
    __syncthreads();
    if (tid == 0){
      __hip_atomic_fetch_add(&cnt[(bid & 7)*32], 1u, __ATOMIC_RELEASE, __HIP_MEMORY_SCOPE_AGENT);
      if (bid == 0){
        unsigned tgt = 32u * (unsigned)(it + 1);
        long guard = 0;
        for (;;){
          bool ok = true;
          for (int i2 = 0; i2 < 8; i2++)
            if (__hip_atomic_load(&cnt[i2*32], __ATOMIC_RELAXED, __HIP_MEMORY_SCOPE_AGENT) < tgt){ ok = false; break; }
          if (ok || ++guard > (1L << 28)) break;
        }
        __hip_atomic_store(epoch, (unsigned)(it + 1), __ATOMIC_RELEASE, __HIP_MEMORY_SCOPE_AGENT);
      }
      unsigned e; long guard = 0;
      do {
        e = __hip_atomic_load(epoch, __ATOMIC_RELAXED, __HIP_MEMORY_SCOPE_AGENT);
      } while (e < (unsigned)(it + 1) && ++guard < (1L << 28));
      (void)__hip_atomic_load(epoch, __ATOMIC_ACQUIRE, __HIP_MEMORY_SCOPE_AGENT);  // buffer_inv
    }
    __syncthreads();
  }
}

__global__ __launch_bounds__(256, 1) void lstm_pk(
    const float* __restrict__ x,
    const float* __restrict__ Wih0, const float* __restrict__ Whh0,
    const float* __restrict__ bih0, const float* __restrict__ bhh0,
    const float* __restrict__ Wih1, const float* __restrict__ Whh1,
    const float* __restrict__ bih1, const float* __restrict__ bhh1,
    char* __restrict__ ws)
{
  __shared__ float partial[4*64*33];   // padded: stride 33 breaks bank conflicts
  __shared__ float c_st[64*8];
  __shared__ float biasv[32];

  unsigned* cnt   = (unsigned*)ws;                 // 8 counters, 128B apart
  unsigned* epoch = (unsigned*)(ws + 1024);
  unsigned short* h0r = (unsigned short*)(ws + 4096);            // 2 x [64][1024] bf16
  unsigned short* h1r = (unsigned short*)(ws + 4096 + 262144);   // 2 x [64][1024] bf16
  float* h1f = (float*)(ws + 4096 + 524288);                     // [64][1024] fp32

  const int bid = blockIdx.x;
  if (bid < 128)
    run_lstm<0>(x, Wih0, Whh0, bih0, bhh0, cnt, epoch, h0r, h1r, h1f, bid*8, partial, c_st, biasv);
  else
    run_lstm<1>(x, Wih1, Whh1, bih1, bhh1, cnt, epoch, h0r, h1r, h1f, (bid - 128)*8, partial, c_st, biasv);
}

__global__ __launch_bounds__(128) void fc_k(
    const float* __restrict__ h1f, const float* __restrict__ Wfc,
    const float* __restrict__ bfc, float* __restrict__ out)
{
  __shared__ float hv[1024];
  int b = blockIdx.x, c = threadIdx.x;
  for (int i = c; i < 1024; i += 128) hv[i] = h1f[(size_t)b*1024 + i];
  __syncthreads();
  const floatx4* w4 = (const floatx4*)(Wfc + (size_t)c*1024);
  const floatx4* h4 = (const floatx4*)hv;
  float acc = 0.f;
  #pragma unroll 8
  for (int k = 0; k < 256; k++){
    floatx4 wv = w4[k];
    floatx4 hh = h4[k];
    acc += wv[0]*hh[0] + wv[1]*hh[1] + wv[2]*hh[2] + wv[3]*hh[3];
  }
  out[(size_t)b*128 + c] = acc + bfc[c];
}

extern "C" void kernel_launch(void* const* d_in, const int* in_sizes, int n_in,
                              void* d_out, int out_size, void* d_ws, size_t ws_size,
                              hipStream_t stream)
{
  const float* x    = (const float*)d_in[0];
  const float* Wih0 = (const float*)d_in[1];
  const float* Whh0 = (const float*)d_in[2];
  const float* bih0 = (const float*)d_in[3];
  const float* bhh0 = (const float*)d_in[4];
  const float* Wih1 = (const float*)d_in[5];
  const float* Whh1 = (const float*)d_in[6];
  const float* bih1 = (const float*)d_in[7];
  const float* bhh1 = (const float*)d_in[8];
  const float* Wfc  = (const float*)d_in[9];
  const float* bfc  = (const float*)d_in[10];

  // zero barrier state + both h rings (h[-1] = 0)
  hipMemsetAsync(d_ws, 0, 4096 + 524288, stream);

  lstm_pk<<<256, 256, 0, stream>>>(x, Wih0, Whh0, bih0, bhh0, Wih1, Whh1, bih1, bhh1, (char*)d_ws);

  const float* h1f = (const float*)((char*)d_ws + 4096 + 524288);
  fc_k<<<64, 128, 0, stream>>>(h1f, Wfc, bfc, (float*)d_out);
}

// Round 2
// 8645.168 us; speedup vs baseline: 2.4223x; 2.4223x over previous
//
#include <hip/hip_runtime.h>
#include <hip/hip_bf16.h>

#define B_ 64
#define T_ 512
#define D_ 256
#define H_ 1024
#define RING 64          // h-history ring depth (slot reuse after 64 steps)
#define NBLK 64          // blocks per layer
#define FSTRIDE 16       // uints per flag line (64 B)

typedef __attribute__((ext_vector_type(8))) short short8;
typedef __attribute__((ext_vector_type(4))) float floatx4;

__device__ __forceinline__ unsigned short f2bf(float f){
  unsigned u = __builtin_bit_cast(unsigned, f);
  u = (u + 0x7fffu + ((u >> 16) & 1u)) >> 16;
  return (unsigned short)u;
}

__device__ __forceinline__ short8 pack8(floatx4 a, floatx4 b){
  short8 r;
  r[0]=(short)f2bf(a[0]); r[1]=(short)f2bf(a[1]); r[2]=(short)f2bf(a[2]); r[3]=(short)f2bf(a[3]);
  r[4]=(short)f2bf(b[0]); r[5]=(short)f2bf(b[1]); r[6]=(short)f2bf(b[2]); r[7]=(short)f2bf(b[3]);
  return r;
}

__device__ __forceinline__ float sigm(float v){ return 1.f/(1.f+__expf(-v)); }
__device__ __forceinline__ float tanh_f(float v){ return 1.f - 2.f/(1.f+__expf(2.f*v)); }

__device__ __forceinline__ void waitflag(unsigned* p, unsigned tgt){
  long g = 0;
  while (__hip_atomic_load(p, __ATOMIC_RELAXED, __HIP_MEMORY_SCOPE_AGENT) < tgt){
    __builtin_amdgcn_s_sleep(2);
    if (++g > (1L<<24)) break;   // safety valve against GPU hang; never hit in correct runs
  }
}

// LAYER 0: K = 256 (x, fp32) + 1024 (h0).  LAYER 1: K = 1024 (h0) + 1024 (h1).
// Block: 512 threads = 8 waves = 4 K-slices x 2 N-halves; owns 16 h-columns (64 gate rows).
template<int LAYER>
__device__ __forceinline__ void run_lstm(
    const float* __restrict__ x,
    const float* __restrict__ Wi, const float* __restrict__ Wh,
    const float* __restrict__ bi, const float* __restrict__ bh,
    unsigned* flags, unsigned short* h0h, unsigned short* h1h, float* h1f,
    int jbase, float* partial /*[4][64][66]*/, float* c_st /*[64][16]*/, float* biasv /*[64]*/)
{
  constexpr int KTOT = LAYER ? 2048 : 1280;
  constexpr int KW   = KTOT/4;          // per-k-slice K extent (512 / 320)
  constexpr int NK   = KW/32;           // k-steps per wave (16 / 10)
  constexpr int KA   = LAYER ? 1024 : 256;  // "always live at t=0" boundary (= Wi K extent)

  const int tid   = threadIdx.x;
  const int wave  = tid >> 6;
  const int lane  = tid & 63;
  const int nhalf = wave >> 2;          // which 32 gate rows
  const int ksl   = wave & 3;           // which K slice
  const int n15   = lane & 15;
  const int kq    = (lane >> 4) * 8;

  // ---- one-time: weights -> registers (bf16). 2 n-tiles x NK k-steps per wave.
  short8 bfr[2][NK];
  #pragma unroll
  for (int nt = 0; nt < 2; nt++){
    int n   = nhalf*32 + nt*16 + n15;
    int row = (n >> 4)*H_ + jbase + (n & 15);
    #pragma unroll
    for (int ks = 0; ks < NK; ks++){
      int k = ksl*KW + ks*32 + kq;
      const float* s = (k < KA) ? (Wi + (size_t)row*KA + k)
                                : (Wh + (size_t)row*H_ + (k - KA));
      bfr[nt][ks] = pack8(*(const floatx4*)s, *(const floatx4*)(s + 4));
    }
  }
  if (tid < 64){
    int n = tid;
    int col = (n >> 4)*H_ + jbase + (n & 15);
    biasv[n] = bi[col] + bh[col];
  }
  c_st[tid] = 0.f; c_st[tid + 512] = 0.f;
  __syncthreads();

  unsigned* f0 = flags;
  unsigned* f1 = flags + T_*FSTRIDE;

  for (int t = 0; t < T_; t++){
    // ---- dataflow waits (RELAXED agent polls; no cache maintenance)
    if (tid == 0){
      if (LAYER == 0){
        if (t > 0)     waitflag(f0 + (t-1)*FSTRIDE, NBLK);   // RAW: h0[t-1]
        if (t >= RING) waitflag(f1 + (t-RING)*FSTRIDE, NBLK);// WAR: ring slot reuse vs layer-1 readers
      } else {
        waitflag(f0 + t*FSTRIDE, NBLK);                      // RAW: h0[t]
        if (t > 0) waitflag(f1 + (t-1)*FSTRIDE, NBLK);       // RAW: h1[t-1] (also covers WAR, depth>=2)
      }
    }
    __syncthreads();

    floatx4 acc[4][2];
    #pragma unroll
    for (int mt = 0; mt < 4; mt++)
      #pragma unroll
      for (int nt = 0; nt < 2; nt++)
        acc[mt][nt] = (floatx4)0.f;

    const unsigned short* h0t = h0h + (size_t)((LAYER ? t : (t-1)) & (RING-1)) * (B_*H_);
    const unsigned short* h1t = h1h + (size_t)((t-1) & (RING-1)) * (B_*H_);

    #pragma unroll
    for (int ks = 0; ks < NK; ks++){
      const int kb = ksl*KW + ks*32;
      if (kb >= KA && t == 0) continue;   // h[-1] = 0: skip (wave-uniform)
      const int kk = kb + kq;
      short8 afr[4];
      if constexpr (LAYER == 0){
        if (kb < 256){
          #pragma unroll
          for (int mt = 0; mt < 4; mt++){
            const float* xs = x + ((size_t)(mt*16 + n15)*T_ + t)*D_ + kk;
            afr[mt] = pack8(*(const floatx4*)xs, *(const floatx4*)(xs + 4));
          }
        } else {
          const unsigned short* base = h0t + (kk - 256);
          #pragma unroll
          for (int mt = 0; mt < 4; mt++)
            afr[mt] = *(const short8*)(base + (size_t)(mt*16 + n15)*H_);
        }
      } else {
        const unsigned short* base = (kb < 1024) ? (h0t + kk) : (h1t + (kk - 1024));
        #pragma unroll
        for (int mt = 0; mt < 4; mt++)
          afr[mt] = *(const short8*)(base + (size_t)(mt*16 + n15)*H_);
      }
      #pragma unroll
      for (int mt = 0; mt < 4; mt++)
        #pragma unroll
        for (int nt = 0; nt < 2; nt++)
          acc[mt][nt] = __builtin_amdgcn_mfma_f32_16x16x32_bf16(afr[mt], bfr[nt][ks], acc[mt][nt], 0, 0, 0);
    }

    // ---- spill K-slice partials to LDS (C layout: col=lane&15, row=(lane>>4)*4+r)
    #pragma unroll
    for (int mt = 0; mt < 4; mt++)
      #pragma unroll
      for (int nt = 0; nt < 2; nt++)
        #pragma unroll
        for (int r = 0; r < 4; r++){
          int b = mt*16 + (lane >> 4)*4 + r;
          int n = nhalf*32 + nt*16 + n15;
          partial[((size_t)ksl*64 + b)*66 + n] = acc[mt][nt][r];
        }
    __syncthreads();

    // ---- gate reduction + nonlinearities + write-through h store
    {
      int b = tid >> 3, jj0 = (tid & 7)*2;
      unsigned short hb[2]; float hf[2];
      #pragma unroll
      for (int u = 0; u < 2; u++){
        int jj = jj0 + u;
        float g[4];
        #pragma unroll
        for (int q = 0; q < 4; q++){
          int n = q*16 + jj;
          g[q] = partial[(0*64 + b)*66 + n] + partial[(1*64 + b)*66 + n]
               + partial[(2*64 + b)*66 + n] + partial[(3*64 + b)*66 + n] + biasv[n];
        }
        float co = c_st[b*16 + jj];
        float si = sigm(g[0]), sf = sigm(g[1]), tg = tanh_f(g[2]), so = sigm(g[3]);
        float cn = sf*co + si*tg;
        float hn = so*tanh_f(cn);
        c_st[b*16 + jj] = cn;
        hb[u] = f2bf(hn); hf[u] = hn;
      }
      unsigned pk = (unsigned)hb[0] | ((unsigned)hb[1] << 16);
      unsigned short* dst = (LAYER ? h1h : h0h)
                          + (size_t)(t & (RING-1))*(B_*H_) + (size_t)b*H_ + jbase + jj0;
      __hip_atomic_store((unsigned*)dst, pk, __ATOMIC_RELAXED, __HIP_MEMORY_SCOPE_AGENT); // sc1: straight to LLC
      if (LAYER == 1 && t == T_-1){
        h1f[(size_t)b*H_ + jbase + jj0]     = hf[0];
        h1f[(size_t)b*H_ + jbase + jj0 + 1] = hf[1];
      }
    }
    __syncthreads();   // drains vmcnt in every wave before the flag post
    if (tid == 0)
      __hip_atomic_fetch_add((LAYER ? f1 : f0) + t*FSTRIDE, 1u,
                             __ATOMIC_RELAXED, __HIP_MEMORY_SCOPE_AGENT);
  }
}

__global__ __launch_bounds__(512, 2) void lstm_pk(
    const float* __restrict__ x,
    const float* __restrict__ Wih0, const float* __restrict__ Whh0,
    const float* __restrict__ bih0, const float* __restrict__ bhh0,
    const float* __restrict__ Wih1, const float* __restrict__ Whh1,
    const float* __restrict__ bih1, const float* __restrict__ bhh1,
    char* __restrict__ ws)
{
  __shared__ float partial[4*64*66];   // 67.6 KB, stride 66 -> 2-way banks (free)
  __shared__ float c_st[1024];
  __shared__ float biasv[64];

  unsigned* flags     = (unsigned*)ws;                                    // 2 x 512 x 64 B
  unsigned short* h0h = (unsigned short*)(ws + (1<<20));                  // RING x [64][1024] bf16 (8 MB)
  unsigned short* h1h = (unsigned short*)(ws + (1<<20) + RING*B_*H_*2);   // 8 MB
  float* h1f          = (float*)(ws + (1<<20) + 2*(size_t)RING*B_*H_*2);  // [64][1024] fp32

  const int bid = blockIdx.x;
  if (bid < NBLK)
    run_lstm<0>(x, Wih0, Whh0, bih0, bhh0, flags, h0h, h1h, h1f, bid*16, partial, c_st, biasv);
  else
    run_lstm<1>(x, Wih1, Whh1, bih1, bhh1, flags, h0h, h1h, h1f, (bid-NBLK)*16, partial, c_st, biasv);
}

__global__ __launch_bounds__(128) void fc_k(
    const float* __restrict__ h1f, const float* __restrict__ Wfc,
    const float* __restrict__ bfc, float* __restrict__ out)
{
  __shared__ float hv[1024];
  int b = blockIdx.x, c = threadIdx.x;
  for (int i = c; i < 1024; i += 128) hv[i] = h1f[(size_t)b*1024 + i];
  __syncthreads();
  const floatx4* w4 = (const floatx4*)(Wfc + (size_t)c*1024);
  const floatx4* h4 = (const floatx4*)hv;
  float acc = 0.f;
  #pragma unroll 8
  for (int k = 0; k < 256; k++){
    floatx4 wv = w4[k];
    floatx4 hh = h4[k];
    acc += wv[0]*hh[0] + wv[1]*hh[1] + wv[2]*hh[2] + wv[3]*hh[3];
  }
  out[(size_t)b*128 + c] = acc + bfc[c];
}

extern "C" void kernel_launch(void* const* d_in, const int* in_sizes, int n_in,
                              void* d_out, int out_size, void* d_ws, size_t ws_size,
                              hipStream_t stream)
{
  const float* x    = (const float*)d_in[0];
  const float* Wih0 = (const float*)d_in[1];
  const float* Whh0 = (const float*)d_in[2];
  const float* bih0 = (const float*)d_in[3];
  const float* bhh0 = (const float*)d_in[4];
  const float* Wih1 = (const float*)d_in[5];
  const float* Whh1 = (const float*)d_in[6];
  const float* bih1 = (const float*)d_in[7];
  const float* bhh1 = (const float*)d_in[8];
  const float* Wfc  = (const float*)d_in[9];
  const float* bfc  = (const float*)d_in[10];

  // zero only the flag region (h ring slots are written before first read; h[-1] handled by predication)
  hipMemsetAsync(d_ws, 0, 2*T_*FSTRIDE*sizeof(unsigned), stream);

  lstm_pk<<<2*NBLK, 512, 0, stream>>>(x, Wih0, Whh0, bih0, bhh0, Wih1, Whh1, bih1, bhh1, (char*)d_ws);

  const float* h1f = (const float*)((char*)d_ws + (1<<20) + 2*(size_t)RING*B_*H_*2);
  fc_k<<<64, 128, 0, stream>>>(h1f, Wfc, bfc, (float*)d_out);
}

// Round 3
// 8545.147 us; speedup vs baseline: 2.4507x; 1.0117x over previous
//
#include <hip/hip_runtime.h>
#include <hip/hip_bf16.h>

#define B_ 64
#define T_ 512
#define D_ 256
#define H_ 1024
#define RING 64          // h-history ring depth (slot reuse after 64 steps)
#define NBLK 64          // blocks per layer
#define SLOTU 16         // uints per seq slot (64 B line per producer block)

typedef __attribute__((ext_vector_type(8))) short short8;
typedef __attribute__((ext_vector_type(4))) float floatx4;

__device__ __forceinline__ unsigned short f2bf(float f){
  unsigned u = __builtin_bit_cast(unsigned, f);
  u = (u + 0x7fffu + ((u >> 16) & 1u)) >> 16;
  return (unsigned short)u;
}

__device__ __forceinline__ short8 pack8(floatx4 a, floatx4 b){
  short8 r;
  r[0]=(short)f2bf(a[0]); r[1]=(short)f2bf(a[1]); r[2]=(short)f2bf(a[2]); r[3]=(short)f2bf(a[3]);
  r[4]=(short)f2bf(b[0]); r[5]=(short)f2bf(b[1]); r[6]=(short)f2bf(b[2]); r[7]=(short)f2bf(b[3]);
  return r;
}

__device__ __forceinline__ float sigm(float v){ return 1.f/(1.f+__expf(-v)); }
__device__ __forceinline__ float tanh_f(float v){ return 1.f - 2.f/(1.f+__expf(2.f*v)); }

// LAYER 0: K = 256 (x, fp32) + 1024 (h0).  LAYER 1: K = 1024 (h0) + 1024 (h1).
// Block: 512 threads = 8 waves = 4 K-slices x 2 N-halves; owns 16 h-columns (64 gate rows).
template<int LAYER>
__device__ __forceinline__ void run_lstm(
    const float* __restrict__ x,
    const float* __restrict__ Wi, const float* __restrict__ Wh,
    const float* __restrict__ bi, const float* __restrict__ bh,
    unsigned* seq, unsigned short* h0h, unsigned short* h1h, float* h1f,
    int jbase, int myblk,
    float* partial /*[4][64][66]*/, float* c_st /*[64][16]*/, float* biasv /*[64]*/)
{
  constexpr int KTOT = LAYER ? 2048 : 1280;
  constexpr int KW   = KTOT/4;          // per-k-slice K extent (512 / 320)
  constexpr int NK   = KW/32;           // k-steps per wave (16 / 10)
  constexpr int KA   = LAYER ? 1024 : 256;  // Wi K extent (h part starts here)

  const int tid   = threadIdx.x;
  const int wave  = tid >> 6;
  const int lane  = tid & 63;
  const int nhalf = wave >> 2;          // which 32 gate rows
  const int ksl   = wave & 3;           // which K slice
  const int n15   = lane & 15;
  const int kq    = (lane >> 4) * 8;

  // ---- one-time: weights -> registers (bf16). 2 n-tiles x NK k-steps per wave.
  short8 bfr[2][NK];
  #pragma unroll
  for (int nt = 0; nt < 2; nt++){
    int n   = nhalf*32 + nt*16 + n15;
    int row = (n >> 4)*H_ + jbase + (n & 15);
    #pragma unroll
    for (int ks = 0; ks < NK; ks++){
      int k = ksl*KW + ks*32 + kq;
      const float* s = (k < KA) ? (Wi + (size_t)row*KA + k)
                                : (Wh + (size_t)row*H_ + (k - KA));
      bfr[nt][ks] = pack8(*(const floatx4*)s, *(const floatx4*)(s + 4));
    }
  }
  if (tid < 64){
    int n = tid;
    int col = (n >> 4)*H_ + jbase + (n & 15);
    biasv[n] = bi[col] + bh[col];
  }
  c_st[tid] = 0.f; c_st[tid + 512] = 0.f;
  __syncthreads();

  // per-lane watch address: 8B atomic load covers both layers' counters for block `lane`
  unsigned long long* watch = (unsigned long long*)(seq + (size_t)lane*SLOTU);

  for (int t = 0; t < T_; t++){
    // ---- dataflow waits: every wave polls independently (no RMW, no barrier)
    {
      unsigned tgt0, tgt1;
      if (LAYER == 0){ tgt0 = (unsigned)t; tgt1 = (t >= RING) ? (unsigned)(t-RING+1) : 0u; }
      else           { tgt0 = (unsigned)(t+1); tgt1 = (unsigned)t; }
      if (tgt0 | tgt1){
        long g = 0;
        for (;;){
          unsigned long long v = __hip_atomic_load(watch, __ATOMIC_RELAXED, __HIP_MEMORY_SCOPE_AGENT);
          unsigned v0 = (unsigned)v, v1 = (unsigned)(v >> 32);
          if (__all(v0 >= tgt0 && v1 >= tgt1)) break;
          __builtin_amdgcn_s_sleep(1);
          if (++g > (1L<<22)) break;   // safety valve; never hit in correct runs
        }
      }
    }

    floatx4 acc[4][2];
    #pragma unroll
    for (int mt = 0; mt < 4; mt++)
      #pragma unroll
      for (int nt = 0; nt < 2; nt++)
        acc[mt][nt] = (floatx4)0.f;

    const unsigned short* h0t = h0h + (size_t)((LAYER ? t : (t-1)) & (RING-1)) * (B_*H_);
    const unsigned short* h1t = h1h + (size_t)((t-1) & (RING-1)) * (B_*H_);

    #pragma unroll
    for (int ks = 0; ks < NK; ks++){
      const int kb = ksl*KW + ks*32;
      if (kb >= KA && t == 0) continue;   // h[-1] = 0: skip (wave-uniform)
      const int kk = kb + kq;
      short8 afr[4];
      if constexpr (LAYER == 0){
        if (kb < 256){
          #pragma unroll
          for (int mt = 0; mt < 4; mt++){
            const float* xs = x + ((size_t)(mt*16 + n15)*T_ + t)*D_ + kk;
            afr[mt] = pack8(*(const floatx4*)xs, *(const floatx4*)(xs + 4));
          }
        } else {
          const unsigned short* base = h0t + (kk - 256);
          #pragma unroll
          for (int mt = 0; mt < 4; mt++)
            afr[mt] = *(const short8*)(base + (size_t)(mt*16 + n15)*H_);
        }
      } else {
        const unsigned short* base = (kb < 1024) ? (h0t + kk) : (h1t + (kk - 1024));
        #pragma unroll
        for (int mt = 0; mt < 4; mt++)
          afr[mt] = *(const short8*)(base + (size_t)(mt*16 + n15)*H_);
      }
      #pragma unroll
      for (int mt = 0; mt < 4; mt++)
        #pragma unroll
        for (int nt = 0; nt < 2; nt++)
          acc[mt][nt] = __builtin_amdgcn_mfma_f32_16x16x32_bf16(afr[mt], bfr[nt][ks], acc[mt][nt], 0, 0, 0);
    }

    // ---- spill K-slice partials to LDS (C layout: col=lane&15, row=(lane>>4)*4+r)
    #pragma unroll
    for (int mt = 0; mt < 4; mt++)
      #pragma unroll
      for (int nt = 0; nt < 2; nt++)
        #pragma unroll
        for (int r = 0; r < 4; r++){
          int b = mt*16 + (lane >> 4)*4 + r;
          int n = nhalf*32 + nt*16 + n15;
          partial[((size_t)ksl*64 + b)*66 + n] = acc[mt][nt][r];
        }
    __syncthreads();

    // ---- gate reduction + nonlinearities + write-through h store
    {
      int b = tid >> 3, jj0 = (tid & 7)*2;
      unsigned short hb[2]; float hf[2];
      #pragma unroll
      for (int u = 0; u < 2; u++){
        int jj = jj0 + u;
        float g[4];
        #pragma unroll
        for (int q = 0; q < 4; q++){
          int n = q*16 + jj;
          g[q] = partial[(0*64 + b)*66 + n] + partial[(1*64 + b)*66 + n]
               + partial[(2*64 + b)*66 + n] + partial[(3*64 + b)*66 + n] + biasv[n];
        }
        float co = c_st[b*16 + jj];
        float si = sigm(g[0]), sf = sigm(g[1]), tg = tanh_f(g[2]), so = sigm(g[3]);
        float cn = sf*co + si*tg;
        float hn = so*tanh_f(cn);
        c_st[b*16 + jj] = cn;
        hb[u] = f2bf(hn); hf[u] = hn;
      }
      unsigned pk = (unsigned)hb[0] | ((unsigned)hb[1] << 16);
      unsigned short* dst = (LAYER ? h1h : h0h)
                          + (size_t)(t & (RING-1))*(B_*H_) + (size_t)b*H_ + jbase + jj0;
      __hip_atomic_store((unsigned*)dst, pk, __ATOMIC_RELAXED, __HIP_MEMORY_SCOPE_AGENT); // sc1: straight to LLC
      if (LAYER == 1 && t == T_-1){
        h1f[(size_t)b*H_ + jbase + jj0]     = hf[0];
        h1f[(size_t)b*H_ + jbase + jj0 + 1] = hf[1];
      }
    }
    __syncthreads();   // all waves drain vmcnt (h stores visible) before the post
    if (tid == 0)
      __hip_atomic_store(seq + (size_t)myblk*SLOTU + LAYER, (unsigned)(t+1),
                         __ATOMIC_RELAXED, __HIP_MEMORY_SCOPE_AGENT);  // plain store post: no RMW
  }
}

__global__ __launch_bounds__(512, 2) void lstm_pk(
    const float* __restrict__ x,
    const float* __restrict__ Wih0, const float* __restrict__ Whh0,
    const float* __restrict__ bih0, const float* __restrict__ bhh0,
    const float* __restrict__ Wih1, const float* __restrict__ Whh1,
    const float* __restrict__ bih1, const float* __restrict__ bhh1,
    char* __restrict__ ws)
{
  __shared__ float partial[4*64*66];   // 67.6 KB, stride 66 -> 2-way banks (free)
  __shared__ float c_st[1024];
  __shared__ float biasv[64];

  unsigned* seq       = (unsigned*)ws;                                    // 64 slots x 64 B: [j].dword0 = layer0 seq, .dword1 = layer1 seq
  unsigned short* h0h = (unsigned short*)(ws + (1<<20));                  // RING x [64][1024] bf16 (8 MB)
  unsigned short* h1h = (unsigned short*)(ws + (1<<20) + RING*B_*H_*2);   // 8 MB
  float* h1f          = (float*)(ws + (1<<20) + 2*(size_t)RING*B_*H_*2);  // [64][1024] fp32

  const int bid = blockIdx.x;
  if (bid < NBLK)
    run_lstm<0>(x, Wih0, Whh0, bih0, bhh0, seq, h0h, h1h, h1f, bid*16, bid, partial, c_st, biasv);
  else
    run_lstm<1>(x, Wih1, Whh1, bih1, bhh1, seq, h0h, h1h, h1f, (bid-NBLK)*16, bid-NBLK, partial, c_st, biasv);
}

__global__ __launch_bounds__(128) void fc_k(
    const float* __restrict__ h1f, const float* __restrict__ Wfc,
    const float* __restrict__ bfc, float* __restrict__ out)
{
  __shared__ float hv[1024];
  int b = blockIdx.x, c = threadIdx.x;
  for (int i = c; i < 1024; i += 128) hv[i] = h1f[(size_t)b*1024 + i];
  __syncthreads();
  const floatx4* w4 = (const floatx4*)(Wfc + (size_t)c*1024);
  const floatx4* h4 = (const floatx4*)hv;
  float acc = 0.f;
  #pragma unroll 8
  for (int k = 0; k < 256; k++){
    floatx4 wv = w4[k];
    floatx4 hh = h4[k];
    acc += wv[0]*hh[0] + wv[1]*hh[1] + wv[2]*hh[2] + wv[3]*hh[3];
  }
  out[(size_t)b*128 + c] = acc + bfc[c];
}

extern "C" void kernel_launch(void* const* d_in, const int* in_sizes, int n_in,
                              void* d_out, int out_size, void* d_ws, size_t ws_size,
                              hipStream_t stream)
{
  const float* x    = (const float*)d_in[0];
  const float* Wih0 = (const float*)d_in[1];
  const float* Whh0 = (const float*)d_in[2];
  const float* bih0 = (const float*)d_in[3];
  const float* bhh0 = (const float*)d_in[4];
  const float* Wih1 = (const float*)d_in[5];
  const float* Whh1 = (const float*)d_in[6];
  const float* bih1 = (const float*)d_in[7];
  const float* bhh1 = (const float*)d_in[8];
  const float* Wfc  = (const float*)d_in[9];
  const float* bfc  = (const float*)d_in[10];

  // zero only the seq region (h ring slots are written before first read; h[-1] handled by predication)
  hipMemsetAsync(d_ws, 0, NBLK*SLOTU*sizeof(unsigned), stream);

  lstm_pk<<<2*NBLK, 512, 0, stream>>>(x, Wih0, Whh0, bih0, bhh0, Wih1, Whh1, bih1, bhh1, (char*)d_ws);

  const float* h1f = (const float*)((char*)d_ws + (1<<20) + 2*(size_t)RING*B_*H_*2);
  fc_k<<<64, 128, 0, stream>>>(h1f, Wfc, bfc, (float*)d_out);
}